// Round 8
// baseline (480.496 us; speedup 1.0000x reference)
//
#include <hip/hip_runtime.h>
#include <hip/hip_bf16.h>

typedef __bf16 bf16;
typedef __bf16 bf16x4 __attribute__((ext_vector_type(4)));
typedef __bf16 bf16x8 __attribute__((ext_vector_type(8)));
typedef float  f32x4  __attribute__((ext_vector_type(4)));

#define MFMA_16x16x32(a, b, c) __builtin_amdgcn_mfma_f32_16x16x32_bf16((a), (b), (c), 0, 0, 0)

typedef const void __attribute__((address_space(1))) gvoid;
typedef void __attribute__((address_space(3))) svoid;

__device__ __forceinline__ void async_copy16(const void* gptr, void* ldsptr) {
    __builtin_amdgcn_global_load_lds((gvoid*)gptr, (svoid*)ldsptr, 16, 0, 0);
}

// XOR swizzle for [16][32] bf16 LDS segments (row stride 64B).
// slot(row,quad) = quad ^ ((row>>1)&3). Both-sides: pre-swizzled global
// source chunk for global_load_lds (linear dest) + same XOR on ds_read.
__device__ __forceinline__ int swz8(int row, int quad) {
    return (quad ^ ((row >> 1) & 3)) * 8;
}

// Packed f32x2 -> bf16x2 (one u32). T12 recipe: no builtin on gfx950.
__device__ __forceinline__ unsigned cvt_pk_bf16(float a, float b) {
    unsigned r;
    asm("v_cvt_pk_bf16_f32 %0, %1, %2" : "=v"(r) : "v"(a), "v"(b));
    return r;
}

// ---------------------------------------------------------------------------
// Fused f32->bf16 converters.
// ---------------------------------------------------------------------------
__global__ void cvt3_acts(const float* __restrict__ s0, const float* __restrict__ s1,
                          const float* __restrict__ s2,
                          bf16* __restrict__ d0, bf16* __restrict__ d1, bf16* __restrict__ d2)
{
    constexpr int N4SEG = 8192 * 1024 / 4;
    int i = blockIdx.x * blockDim.x + threadIdx.x;
    const int stride = gridDim.x * blockDim.x;
    for (; i < 3 * N4SEG; i += stride) {
        const int seg = i / N4SEG;
        const int j = i - seg * N4SEG;
        const float* s = seg == 0 ? s0 : (seg == 1 ? s1 : s2);
        bf16* d = seg == 0 ? d0 : (seg == 1 ? d1 : d2);
        float4 v = ((const float4*)s)[j];
        bf16x4 o = { (bf16)v.x, (bf16)v.y, (bf16)v.z, (bf16)v.w };
        ((bf16x4*)d)[j] = o;
    }
}

__global__ void cvt5_wts(const float* __restrict__ s0, const float* __restrict__ s1,
                         const float* __restrict__ s2, const float* __restrict__ s3,
                         const float* __restrict__ s4,
                         bf16* __restrict__ d0, bf16* __restrict__ d1, bf16* __restrict__ d2,
                         bf16* __restrict__ d3, bf16* __restrict__ d4)
{
    constexpr int N4SEG = 1024 * 1024 / 4;
    int i = blockIdx.x * blockDim.x + threadIdx.x;
    const int stride = gridDim.x * blockDim.x;
    for (; i < 5 * N4SEG; i += stride) {
        const int seg = i / N4SEG;
        const int j = i - seg * N4SEG;
        const float* s = seg == 0 ? s0 : seg == 1 ? s1 : seg == 2 ? s2 : seg == 3 ? s3 : s4;
        bf16* d = seg == 0 ? d0 : seg == 1 ? d1 : seg == 2 ? d2 : seg == 3 ? d3 : d4;
        float4 v = ((const float4*)s)[j];
        bf16x4 o = { (bf16)v.x, (bf16)v.y, (bf16)v.z, (bf16)v.w };
        ((bf16x4*)d)[j] = o;
    }
}

// ---------------------------------------------------------------------------
// Fused projection GEMM, one dispatch for QR | K | V^T.
// K-tiles double-buffered (kept: ~-11us across proj+gemm_out vs 2-barrier).
// ---------------------------------------------------------------------------
__global__ void proj_fused(const bf16* __restrict__ xq, const bf16* __restrict__ xk,
                           const bf16* __restrict__ xv, const bf16* __restrict__ wall,
                           const float* __restrict__ ball,
                           bf16* __restrict__ qr, bf16* __restrict__ kws,
                           bf16* __restrict__ vtws)
{
    constexpr int K = 1024, SDIM = 2048;
    __shared__ alignas(16) bf16 As[2][128 * 32];
    __shared__ alignas(16) bf16 Bs[2][128 * 32];

    const int tid  = threadIdx.x;
    const int lane = tid & 63;
    const int wave = tid >> 6;
    const int wm   = wave >> 1;
    const int wn   = wave & 1;
    const int bm   = blockIdx.x * 128;
    const int by   = blockIdx.y;
    const int bn   = by * 128;              // global n
    const int l15  = lane & 15;
    const int quad = lane >> 4;

    const bf16* X = (by < 16) ? xq : (by < 24 ? xk : xv);

    const int srow = lane >> 2;
    const int scol = (lane & 3) * 8;

    const bf16* aseg0 = X + (size_t)(bm + wave * 32 + srow) * K + scol;
    const bf16* aseg1 = X + (size_t)(bm + wave * 32 + 16 + srow) * K + scol;
    const bf16* bseg0 = wall + (size_t)(bn + wave * 32 + srow) * K + scol;
    const bf16* bseg1 = wall + (size_t)(bn + wave * 32 + 16 + srow) * K + scol;

    f32x4 acc[4][4] = {};

    // prologue: stage tile 0 into buffer 0
    async_copy16(aseg0, As[0] + (wave * 2 + 0) * 512);
    async_copy16(aseg1, As[0] + (wave * 2 + 1) * 512);
    async_copy16(bseg0, Bs[0] + (wave * 2 + 0) * 512);
    async_copy16(bseg1, Bs[0] + (wave * 2 + 1) * 512);

    for (int k0 = 0; k0 < K; k0 += 32) {
        const int cur = (k0 >> 5) & 1;
        __syncthreads();                     // tile-cur loads retired everywhere
        if (k0 + 32 < K) {
            const int nxt = cur ^ 1;
            async_copy16(aseg0 + k0 + 32, As[nxt] + (wave * 2 + 0) * 512);
            async_copy16(aseg1 + k0 + 32, As[nxt] + (wave * 2 + 1) * 512);
            async_copy16(bseg0 + k0 + 32, Bs[nxt] + (wave * 2 + 0) * 512);
            async_copy16(bseg1 + k0 + 32, Bs[nxt] + (wave * 2 + 1) * 512);
        }

        bf16x8 af[4], bfr[4];
        #pragma unroll
        for (int i = 0; i < 4; ++i)
            af[i] = *(const bf16x8*)(As[cur] + (wm * 64 + i * 16 + l15) * 32 + quad * 8);
        #pragma unroll
        for (int j = 0; j < 4; ++j)
            bfr[j] = *(const bf16x8*)(Bs[cur] + (wn * 64 + j * 16 + l15) * 32 + quad * 8);
        #pragma unroll
        for (int i = 0; i < 4; ++i)
            #pragma unroll
            for (int j = 0; j < 4; ++j)
                acc[i][j] = MFMA_16x16x32(af[i], bfr[j], acc[i][j]);
    }

    #pragma unroll
    for (int i = 0; i < 4; ++i) {
        const int rowg = bm + wm * 64 + i * 16 + quad * 4;
        #pragma unroll
        for (int j = 0; j < 4; ++j) {
            const int colg = bn + wn * 64 + j * 16 + l15;
            const float bv = ball[colg];
            if (by < 16) {
                #pragma unroll
                for (int r = 0; r < 4; ++r)
                    qr[(size_t)(rowg + r) * 2048 + colg] = (bf16)(acc[i][j][r] + bv);
            } else if (by < 24) {
                const int cl = colg - 2048;
                #pragma unroll
                for (int r = 0; r < 4; ++r)
                    kws[(size_t)(rowg + r) * 1024 + cl] = (bf16)(acc[i][j][r] + bv);
            } else {
                const int d = colg - 3072;
                bf16x4 o;
                #pragma unroll
                for (int r = 0; r < 4; ++r) o[r] = (bf16)(acc[i][j][r] + bv);
                *(bf16x4*)(vtws + (size_t)(rowg >> 11) * 1024 * SDIM
                                + (size_t)d * SDIM + (rowg & (SDIM - 1))) = o;
            }
        }
    }
}

// ---------------------------------------------------------------------------
// Output GEMM: Y[m][n] = sum_k X[m][k]*W[n][k] + b[n], f32 out. Double-buffered.
// ---------------------------------------------------------------------------
__global__ void gemm_out(const bf16* __restrict__ X, const bf16* __restrict__ W,
                         const float* __restrict__ bias, float* __restrict__ Y)
{
    constexpr int K = 1024, N = 1024;
    __shared__ alignas(16) bf16 As[2][128 * 32];
    __shared__ alignas(16) bf16 Bs[2][128 * 32];

    const int tid  = threadIdx.x;
    const int lane = tid & 63;
    const int wave = tid >> 6;
    const int wm   = wave >> 1;
    const int wn   = wave & 1;
    const int bm   = blockIdx.x * 128;
    const int bn   = blockIdx.y * 128;
    const int l15  = lane & 15;
    const int quad = lane >> 4;

    const int srow = lane >> 2;
    const int scol = (lane & 3) * 8;

    const bf16* aseg0 = X + (size_t)(bm + wave * 32 + srow) * K + scol;
    const bf16* aseg1 = X + (size_t)(bm + wave * 32 + 16 + srow) * K + scol;
    const bf16* bseg0 = W + (size_t)(bn + wave * 32 + srow) * K + scol;
    const bf16* bseg1 = W + (size_t)(bn + wave * 32 + 16 + srow) * K + scol;

    f32x4 acc[4][4] = {};

    async_copy16(aseg0, As[0] + (wave * 2 + 0) * 512);
    async_copy16(aseg1, As[0] + (wave * 2 + 1) * 512);
    async_copy16(bseg0, Bs[0] + (wave * 2 + 0) * 512);
    async_copy16(bseg1, Bs[0] + (wave * 2 + 1) * 512);

    for (int k0 = 0; k0 < K; k0 += 32) {
        const int cur = (k0 >> 5) & 1;
        __syncthreads();
        if (k0 + 32 < K) {
            const int nxt = cur ^ 1;
            async_copy16(aseg0 + k0 + 32, As[nxt] + (wave * 2 + 0) * 512);
            async_copy16(aseg1 + k0 + 32, As[nxt] + (wave * 2 + 1) * 512);
            async_copy16(bseg0 + k0 + 32, Bs[nxt] + (wave * 2 + 0) * 512);
            async_copy16(bseg1 + k0 + 32, Bs[nxt] + (wave * 2 + 1) * 512);
        }

        bf16x8 af[4], bfr[4];
        #pragma unroll
        for (int i = 0; i < 4; ++i)
            af[i] = *(const bf16x8*)(As[cur] + (wm * 64 + i * 16 + l15) * 32 + quad * 8);
        #pragma unroll
        for (int j = 0; j < 4; ++j)
            bfr[j] = *(const bf16x8*)(Bs[cur] + (wn * 64 + j * 16 + l15) * 32 + quad * 8);
        #pragma unroll
        for (int i = 0; i < 4; ++i)
            #pragma unroll
            for (int j = 0; j < 4; ++j)
                acc[i][j] = MFMA_16x16x32(af[i], bfr[j], acc[i][j]);
    }

    #pragma unroll
    for (int i = 0; i < 4; ++i) {
        const int rowg = bm + wm * 64 + i * 16 + quad * 4;
        #pragma unroll
        for (int j = 0; j < 4; ++j) {
            const int colg = bn + wn * 64 + j * 16 + l15;
            const float bv = bias[colg];
            #pragma unroll
            for (int r = 0; r < 4; ++r)
                Y[(size_t)(rowg + r) * N + colg] = acc[i][j][r] + bv;
        }
    }
}

// ---------------------------------------------------------------------------
// Streaming attention + R-gating. Back to the best-measured R1 geometry:
// 4 waves x 32 q-rows (mi=2), 128 rows/block, grid 1024 (4 blk/CU).
// This round (after mi=4 falsified the LDS-BW theory):
//  * V is NOT staged in LDS at all (m169 precedent: K/V L2-fits). Each wave
//    reads its V fragments directly from global Vt with b128 loads (16 full
//    64B lines per instr — same line count as the staged path), issued at
//    the top of the iter and consumed in PV ~600cy later: vmcnt-pipelined,
//    not barrier-locked. Removes 2 async copies + 8 LDS reads/iter + V's
//    share of the barrier drain and LDS bank pressure.
//  * K-only double-buffer (16KB): one barrier/iter, K loads in flight
//    across the whole compute phase. LDS total 36.9KB -> 4 blocks/CU kept.
//  * Pt back to wide per-(mi,half) layout, pack-all-then-PV-all (max
//    write->read distance; the R4/R7 shared-Pt serialization was a small
//    pessimization).
//  * P packing via v_cvt_pk_bf16_f32 (2 issues instead of 4 cvts per nb).
//  * K XOR-swizzled (swz8); denominator on MFMA pipe (ones x P^T).
// ---------------------------------------------------------------------------
__launch_bounds__(256, 2)
__global__ void attn_fused(const bf16* __restrict__ QRp, const bf16* __restrict__ Kp,
                           const bf16* __restrict__ Vtp, bf16* __restrict__ Op)
{
    constexpr int S = 2048, DXc = 1024, QRST = 2048, Dh = 64;
    constexpr int PST = 40;                     // P^T row stride (elements)
    constexpr int NT = S / 64;
    __shared__ alignas(16) bf16 Ks[2][2][64 * 32];       // [buf][dhalf][row*32]
    __shared__ alignas(16) bf16 Pt[4][2][2][16 * PST];   // [wave][mi][kvhalf]

    const int tid  = threadIdx.x;
    const int lane = tid & 63;
    const int wave = tid >> 6;
    const int qt = blockIdx.x, h = blockIdx.y, b = blockIdx.z;
    const int l15  = lane & 15;
    const int quad = lane >> 4;

    const size_t qrbase = ((size_t)b * S) * QRST + h * Dh;   // Q cols; R at +1024
    const size_t kbase  = ((size_t)b * S) * DXc + h * Dh;
    const size_t vtbase = ((size_t)(b * 16 + h) * Dh) * S;
    const size_t obase  = ((size_t)b * S) * DXc + h * Dh;

    const int srow = lane >> 2;
    // pre-swizzled source chunk (see swz8)
    const int scol = ((lane & 3) ^ ((srow >> 1) & 3)) * 8;
    const bf16* kseg = Kp + kbase + (size_t)(16 * wave + srow) * DXc + scol;
    const int soff = wave * 512;

    // per-wave V fragment base: row d = db*16+l15, col kv = kv0+half*32+quad*8
    const bf16* vwp = Vtp + vtbase + (size_t)l15 * S + quad * 8;

    // stage K tile 0 into buf 0 — latency hides under the Q prologue
    async_copy16(kseg,      &Ks[0][0][soff]);
    async_copy16(kseg + 32, &Ks[0][1][soff]);

    constexpr float QSCALE = 0.125f * 1.44269504088896340736f;
    bf16x8 qf[2][2];
    #pragma unroll
    for (int mi = 0; mi < 2; ++mi) {
        const int qrow = qt * 128 + wave * 32 + mi * 16 + l15;
        const bf16* qptr = QRp + qrbase + (size_t)qrow * QRST + quad * 8;
        qf[mi][0] = *(const bf16x8*)(qptr);
        qf[mi][1] = *(const bf16x8*)(qptr + 32);
        #pragma unroll
        for (int j = 0; j < 8; ++j) {
            qf[mi][0][j] = (bf16)((float)qf[mi][0][j] * QSCALE);
            qf[mi][1][j] = (bf16)((float)qf[mi][1][j] * QSCALE);
        }
    }

    bf16x8 onef;
    #pragma unroll
    for (int j = 0; j < 8; ++j) onef[j] = (bf16)1.0f;

    f32x4 oacc[2][4] = {};     // [mi][db] — O^T: col=qrow(l15), rows d=quad*4+r
    f32x4 lsacc[2] = {};       // denominator via ones x P^T

    for (int t = 0; t < NT; ++t) {
        const int cur = t & 1;
        const int kv0 = t * 64;
        __syncthreads();                 // K buf[cur] (tile t) retired everywhere
        if (t + 1 < NT) {
            const int nxt = cur ^ 1;
            const size_t ko = (size_t)(t + 1) * 64 * DXc;
            async_copy16(kseg + ko,      &Ks[nxt][0][soff]);
            async_copy16(kseg + ko + 32, &Ks[nxt][1][soff]);
        }

        // ---- V fragments: direct global b128, issued early, used in PV ----
        bf16x8 vtf[2][4];
        #pragma unroll
        for (int half = 0; half < 2; ++half)
            #pragma unroll
            for (int db = 0; db < 4; ++db)
                vtf[half][db] = *(const bf16x8*)(vwp + (size_t)(db * 16) * S
                                                 + kv0 + half * 32);

        // ---- QK phase: all 4 nb blocks ----
        f32x4 st[2][4];
        #pragma unroll
        for (int nb = 0; nb < 4; ++nb) {
            bf16x8 kf0 = *(const bf16x8*)(&Ks[cur][0][0] + (nb * 16 + l15) * 32 + swz8(l15, quad));
            bf16x8 kf1 = *(const bf16x8*)(&Ks[cur][1][0] + (nb * 16 + l15) * 32 + swz8(l15, quad));
            #pragma unroll
            for (int mi = 0; mi < 2; ++mi) {
                f32x4 z = {0.f, 0.f, 0.f, 0.f};
                z = MFMA_16x16x32(kf1, qf[mi][1], z);
                st[mi][nb] = MFMA_16x16x32(kf0, qf[mi][0], z);
            }
        }
        // ---- exp2 / cvt_pk pack / b64-write P^T (all, before any read) ----
        #pragma unroll
        for (int mi = 0; mi < 2; ++mi) {
            #pragma unroll
            for (int nb = 0; nb < 4; ++nb) {
                const float p0 = __builtin_exp2f(st[mi][nb][0]);
                const float p1 = __builtin_exp2f(st[mi][nb][1]);
                const float p2 = __builtin_exp2f(st[mi][nb][2]);
                const float p3 = __builtin_exp2f(st[mi][nb][3]);
                uint2 w;
                w.x = cvt_pk_bf16(p0, p1);
                w.y = cvt_pk_bf16(p2, p3);
                *(uint2*)(&Pt[wave][mi][nb >> 1][0] + l15 * PST
                          + (nb & 1) * 16 + quad * 4) = w;
            }
        }
        // ---- PV phase: K=32, A=Vt reg frags, B=P^T b128 reads ----
        #pragma unroll
        for (int half = 0; half < 2; ++half) {
            #pragma unroll
            for (int mi = 0; mi < 2; ++mi) {
                bf16x8 pf = *(const bf16x8*)(&Pt[wave][mi][half][0]
                                             + l15 * PST + quad * 8);
                #pragma unroll
                for (int db = 0; db < 4; ++db)
                    oacc[mi][db] = MFMA_16x16x32(vtf[half][db], pf, oacc[mi][db]);
                lsacc[mi] = MFMA_16x16x32(onef, pf, lsacc[mi]);
            }
        }
    }

    // epilogue: O^T — col=qrow=l15 (single inv), rows d contiguous bf16x4.
    #pragma unroll
    for (int mi = 0; mi < 2; ++mi) {
        const float inv = 1.0f / lsacc[mi][0];
        const int qrow = qt * 128 + wave * 32 + mi * 16 + l15;
        const bf16* rrow = QRp + qrbase + (size_t)qrow * QRST + 1024;
        bf16* orow = Op + obase + (size_t)qrow * DXc;
        #pragma unroll
        for (int db = 0; db < 4; ++db) {
            bf16x4 rg = *(const bf16x4*)(rrow + db * 16 + quad * 4);
            bf16x4 o;
            #pragma unroll
            for (int r = 0; r < 4; ++r)
                o[r] = (bf16)(oacc[mi][db][r] * inv * (float)rg[r]);
            *(bf16x4*)(orow + db * 16 + quad * 4) = o;
        }
    }
}

extern "C" void kernel_launch(void* const* d_in, const int* in_sizes, int n_in,
                              void* d_out, int out_size, void* d_ws, size_t ws_size,
                              hipStream_t stream)
{
    (void)in_sizes; (void)n_in; (void)out_size; (void)ws_size;
    constexpr int B = 4, S = 2048, DX = 1024, M = B * S;
    constexpr size_t MD = (size_t)M * DX;
    constexpr size_t WD = (size_t)DX * DX;

    const float* value  = (const float*)d_in[0];
    const float* keyi   = (const float*)d_in[1];
    const float* query  = (const float*)d_in[2];
    const float* Wq_w   = (const float*)d_in[3];
    const float* Wq_b   = (const float*)d_in[4];
    const float* Wk_w   = (const float*)d_in[5];
    const float* Wk_b   = (const float*)d_in[6];
    const float* Wv_w   = (const float*)d_in[7];
    const float* Wv_b   = (const float*)d_in[8];
    const float* Wr_w   = (const float*)d_in[9];
    const float* Wr_b   = (const float*)d_in[10];
    const float* Wout_w = (const float*)d_in[11];
    const float* Wout_b = (const float*)d_in[12];

    bf16* p = (bf16*)d_ws;
    bf16* xv   = p;  p += MD;
    bf16* xk   = p;  p += MD;
    bf16* xq   = p;  p += MD;
    bf16* wall = p;  p += 4 * WD;   // [Wq; Wr; Wk; Wv]
    bf16* wo   = p;  p += WD;
    bf16* qr   = p;  p += 2 * MD;   // fused Q|R, [M][2048]
    bf16* kws  = p;  p += MD;
    bf16* vtws = p;  p += MD;       // V^T: [B][DX][S]
    float* ball = (float*)p;        // packed bias [4096] f32
    bf16* ows = xv;                 // xv dead after projections

    hipMemcpyAsync(ball,            Wq_b, DX * sizeof(float), hipMemcpyDeviceToDevice, stream);
    hipMemcpyAsync(ball + DX,       Wr_b, DX * sizeof(float), hipMemcpyDeviceToDevice, stream);
    hipMemcpyAsync(ball + 2 * DX,   Wk_b, DX * sizeof(float), hipMemcpyDeviceToDevice, stream);
    hipMemcpyAsync(ball + 3 * DX,   Wv_b, DX * sizeof(float), hipMemcpyDeviceToDevice, stream);

    cvt3_acts<<<dim3(2048), dim3(256), 0, stream>>>(value, keyi, query, xv, xk, xq);
    cvt5_wts <<<dim3(1024), dim3(256), 0, stream>>>(Wq_w, Wr_w, Wk_w, Wv_w, Wout_w,
                                                    wall, wall + WD, wall + 2 * WD,
                                                    wall + 3 * WD, wo);

    proj_fused<<<dim3(M / 128, 32), dim3(256), 0, stream>>>(
        xq, xk, xv, wall, ball, qr, kws, vtws);

    attn_fused<<<dim3(S / 128, 16, B), dim3(256), 0, stream>>>(qr, kws, vtws, ows);

    gemm_out<<<dim3(M / 128, DX / 128), dim3(256), 0, stream>>>(
        ows, wo, Wout_b, (float*)d_out);
}

// Round 9
// 401.729 us; speedup vs baseline: 1.1961x; 1.1961x over previous
//
#include <hip/hip_runtime.h>
#include <hip/hip_bf16.h>

typedef __bf16 bf16;
typedef __bf16 bf16x4 __attribute__((ext_vector_type(4)));
typedef __bf16 bf16x8 __attribute__((ext_vector_type(8)));
typedef float  f32x4  __attribute__((ext_vector_type(4)));

#define MFMA_16x16x32(a, b, c) __builtin_amdgcn_mfma_f32_16x16x32_bf16((a), (b), (c), 0, 0, 0)

typedef const void __attribute__((address_space(1))) gvoid;
typedef void __attribute__((address_space(3))) svoid;

__device__ __forceinline__ void async_copy16(const void* gptr, void* ldsptr) {
    __builtin_amdgcn_global_load_lds((gvoid*)gptr, (svoid*)ldsptr, 16, 0, 0);
}

// XOR swizzle for [16][32] bf16 LDS segments (row stride 64B).
// slot(row,quad) = quad ^ ((row>>1)&3). Both-sides: pre-swizzled global
// source chunk for global_load_lds (linear dest) + same XOR on ds_read.
__device__ __forceinline__ int swz8(int row, int quad) {
    return (quad ^ ((row >> 1) & 3)) * 8;
}

// Packed f32x2 -> bf16x2 (one u32). T12 recipe: no builtin on gfx950.
__device__ __forceinline__ unsigned cvt_pk_bf16(float a, float b) {
    unsigned r;
    asm("v_cvt_pk_bf16_f32 %0, %1, %2" : "=v"(r) : "v"(a), "v"(b));
    return r;
}

// ---------------------------------------------------------------------------
// Fused f32->bf16 converters.
// ---------------------------------------------------------------------------
__global__ void cvt3_acts(const float* __restrict__ s0, const float* __restrict__ s1,
                          const float* __restrict__ s2,
                          bf16* __restrict__ d0, bf16* __restrict__ d1, bf16* __restrict__ d2)
{
    constexpr int N4SEG = 8192 * 1024 / 4;
    int i = blockIdx.x * blockDim.x + threadIdx.x;
    const int stride = gridDim.x * blockDim.x;
    for (; i < 3 * N4SEG; i += stride) {
        const int seg = i / N4SEG;
        const int j = i - seg * N4SEG;
        const float* s = seg == 0 ? s0 : (seg == 1 ? s1 : s2);
        bf16* d = seg == 0 ? d0 : (seg == 1 ? d1 : d2);
        float4 v = ((const float4*)s)[j];
        bf16x4 o = { (bf16)v.x, (bf16)v.y, (bf16)v.z, (bf16)v.w };
        ((bf16x4*)d)[j] = o;
    }
}

// Weights + bias packing fused (removes 4 hipMemcpyAsync graph nodes).
__global__ void cvt5_wts(const float* __restrict__ s0, const float* __restrict__ s1,
                         const float* __restrict__ s2, const float* __restrict__ s3,
                         const float* __restrict__ s4,
                         const float* __restrict__ bq, const float* __restrict__ br,
                         const float* __restrict__ bk, const float* __restrict__ bv,
                         bf16* __restrict__ d0, bf16* __restrict__ d1, bf16* __restrict__ d2,
                         bf16* __restrict__ d3, bf16* __restrict__ d4,
                         float* __restrict__ ball)
{
    constexpr int N4SEG = 1024 * 1024 / 4;
    int i = blockIdx.x * blockDim.x + threadIdx.x;
    const int stride = gridDim.x * blockDim.x;
    if (i < 4096) {
        const int seg = i >> 10, j = i & 1023;
        const float* b = seg == 0 ? bq : seg == 1 ? br : seg == 2 ? bk : bv;
        ball[i] = b[j];
    }
    for (; i < 5 * N4SEG; i += stride) {
        const int seg = i / N4SEG;
        const int j = i - seg * N4SEG;
        const float* s = seg == 0 ? s0 : seg == 1 ? s1 : seg == 2 ? s2 : seg == 3 ? s3 : s4;
        bf16* d = seg == 0 ? d0 : seg == 1 ? d1 : seg == 2 ? d2 : seg == 3 ? d3 : d4;
        float4 v = ((const float4*)s)[j];
        bf16x4 o = { (bf16)v.x, (bf16)v.y, (bf16)v.z, (bf16)v.w };
        ((bf16x4*)d)[j] = o;
    }
}

// ---------------------------------------------------------------------------
// Fused projection GEMM, one dispatch for QR | K | V^T. K-tiles dbuf'd.
// T1 XCD swizzle: consecutive dispatch-order blocks share a B panel (same
// by); chunked remap clusters each XCD on 4 panels instead of touching all.
// ---------------------------------------------------------------------------
__global__ void proj_fused(const bf16* __restrict__ xq, const bf16* __restrict__ xk,
                           const bf16* __restrict__ xv, const bf16* __restrict__ wall,
                           const float* __restrict__ ball,
                           bf16* __restrict__ qr, bf16* __restrict__ kws,
                           bf16* __restrict__ vtws)
{
    constexpr int K = 1024, SDIM = 2048;
    __shared__ alignas(16) bf16 As[2][128 * 32];
    __shared__ alignas(16) bf16 Bs[2][128 * 32];

    // XCD-chunked remap (nwg=2048, 2048%8==0 -> bijective)
    const int lin  = blockIdx.x + 64 * blockIdx.y;
    const int wgid = (lin & 7) * 256 + (lin >> 3);
    const int bxr  = wgid & 63;
    const int by   = wgid >> 6;

    const int tid  = threadIdx.x;
    const int lane = tid & 63;
    const int wave = tid >> 6;
    const int wm   = wave >> 1;
    const int wn   = wave & 1;
    const int bm   = bxr * 128;
    const int bn   = by * 128;              // global n
    const int l15  = lane & 15;
    const int quad = lane >> 4;

    const bf16* X = (by < 16) ? xq : (by < 24 ? xk : xv);

    const int srow = lane >> 2;
    const int scol = (lane & 3) * 8;

    const bf16* aseg0 = X + (size_t)(bm + wave * 32 + srow) * K + scol;
    const bf16* aseg1 = X + (size_t)(bm + wave * 32 + 16 + srow) * K + scol;
    const bf16* bseg0 = wall + (size_t)(bn + wave * 32 + srow) * K + scol;
    const bf16* bseg1 = wall + (size_t)(bn + wave * 32 + 16 + srow) * K + scol;

    f32x4 acc[4][4] = {};

    // prologue: stage tile 0 into buffer 0
    async_copy16(aseg0, As[0] + (wave * 2 + 0) * 512);
    async_copy16(aseg1, As[0] + (wave * 2 + 1) * 512);
    async_copy16(bseg0, Bs[0] + (wave * 2 + 0) * 512);
    async_copy16(bseg1, Bs[0] + (wave * 2 + 1) * 512);

    for (int k0 = 0; k0 < K; k0 += 32) {
        const int cur = (k0 >> 5) & 1;
        __syncthreads();                     // tile-cur loads retired everywhere
        if (k0 + 32 < K) {
            const int nxt = cur ^ 1;
            async_copy16(aseg0 + k0 + 32, As[nxt] + (wave * 2 + 0) * 512);
            async_copy16(aseg1 + k0 + 32, As[nxt] + (wave * 2 + 1) * 512);
            async_copy16(bseg0 + k0 + 32, Bs[nxt] + (wave * 2 + 0) * 512);
            async_copy16(bseg1 + k0 + 32, Bs[nxt] + (wave * 2 + 1) * 512);
        }

        bf16x8 af[4], bfr[4];
        #pragma unroll
        for (int i = 0; i < 4; ++i)
            af[i] = *(const bf16x8*)(As[cur] + (wm * 64 + i * 16 + l15) * 32 + quad * 8);
        #pragma unroll
        for (int j = 0; j < 4; ++j)
            bfr[j] = *(const bf16x8*)(Bs[cur] + (wn * 64 + j * 16 + l15) * 32 + quad * 8);
        #pragma unroll
        for (int i = 0; i < 4; ++i)
            #pragma unroll
            for (int j = 0; j < 4; ++j)
                acc[i][j] = MFMA_16x16x32(af[i], bfr[j], acc[i][j]);
    }

    #pragma unroll
    for (int i = 0; i < 4; ++i) {
        const int rowg = bm + wm * 64 + i * 16 + quad * 4;
        #pragma unroll
        for (int j = 0; j < 4; ++j) {
            const int colg = bn + wn * 64 + j * 16 + l15;
            const float bv = ball[colg];
            if (by < 16) {
                #pragma unroll
                for (int r = 0; r < 4; ++r)
                    qr[(size_t)(rowg + r) * 2048 + colg] = (bf16)(acc[i][j][r] + bv);
            } else if (by < 24) {
                const int cl = colg - 2048;
                #pragma unroll
                for (int r = 0; r < 4; ++r)
                    kws[(size_t)(rowg + r) * 1024 + cl] = (bf16)(acc[i][j][r] + bv);
            } else {
                const int d = colg - 3072;
                bf16x4 o;
                #pragma unroll
                for (int r = 0; r < 4; ++r) o[r] = (bf16)(acc[i][j][r] + bv);
                *(bf16x4*)(vtws + (size_t)(rowg >> 11) * 1024 * SDIM
                                + (size_t)d * SDIM + (rowg & (SDIM - 1))) = o;
            }
        }
    }
}

// ---------------------------------------------------------------------------
// Output GEMM: Y[m][n] = sum_k X[m][k]*W[n][k] + b[n], f32 out. Dbuf'd + T1.
// ---------------------------------------------------------------------------
__global__ void gemm_out(const bf16* __restrict__ X, const bf16* __restrict__ W,
                         const float* __restrict__ bias, float* __restrict__ Y)
{
    constexpr int K = 1024, N = 1024;
    __shared__ alignas(16) bf16 As[2][128 * 32];
    __shared__ alignas(16) bf16 Bs[2][128 * 32];

    // XCD-chunked remap (nwg=512, 512%8==0 -> bijective)
    const int lin  = blockIdx.x + 64 * blockIdx.y;
    const int wgid = (lin & 7) * 64 + (lin >> 3);
    const int bxr  = wgid & 63;
    const int byr  = wgid >> 6;

    const int tid  = threadIdx.x;
    const int lane = tid & 63;
    const int wave = tid >> 6;
    const int wm   = wave >> 1;
    const int wn   = wave & 1;
    const int bm   = bxr * 128;
    const int bn   = byr * 128;
    const int l15  = lane & 15;
    const int quad = lane >> 4;

    const int srow = lane >> 2;
    const int scol = (lane & 3) * 8;

    const bf16* aseg0 = X + (size_t)(bm + wave * 32 + srow) * K + scol;
    const bf16* aseg1 = X + (size_t)(bm + wave * 32 + 16 + srow) * K + scol;
    const bf16* bseg0 = W + (size_t)(bn + wave * 32 + srow) * K + scol;
    const bf16* bseg1 = W + (size_t)(bn + wave * 32 + 16 + srow) * K + scol;

    f32x4 acc[4][4] = {};

    async_copy16(aseg0, As[0] + (wave * 2 + 0) * 512);
    async_copy16(aseg1, As[0] + (wave * 2 + 1) * 512);
    async_copy16(bseg0, Bs[0] + (wave * 2 + 0) * 512);
    async_copy16(bseg1, Bs[0] + (wave * 2 + 1) * 512);

    for (int k0 = 0; k0 < K; k0 += 32) {
        const int cur = (k0 >> 5) & 1;
        __syncthreads();
        if (k0 + 32 < K) {
            const int nxt = cur ^ 1;
            async_copy16(aseg0 + k0 + 32, As[nxt] + (wave * 2 + 0) * 512);
            async_copy16(aseg1 + k0 + 32, As[nxt] + (wave * 2 + 1) * 512);
            async_copy16(bseg0 + k0 + 32, Bs[nxt] + (wave * 2 + 0) * 512);
            async_copy16(bseg1 + k0 + 32, Bs[nxt] + (wave * 2 + 1) * 512);
        }

        bf16x8 af[4], bfr[4];
        #pragma unroll
        for (int i = 0; i < 4; ++i)
            af[i] = *(const bf16x8*)(As[cur] + (wm * 64 + i * 16 + l15) * 32 + quad * 8);
        #pragma unroll
        for (int j = 0; j < 4; ++j)
            bfr[j] = *(const bf16x8*)(Bs[cur] + (wn * 64 + j * 16 + l15) * 32 + quad * 8);
        #pragma unroll
        for (int i = 0; i < 4; ++i)
            #pragma unroll
            for (int j = 0; j < 4; ++j)
                acc[i][j] = MFMA_16x16x32(af[i], bfr[j], acc[i][j]);
    }

    #pragma unroll
    for (int i = 0; i < 4; ++i) {
        const int rowg = bm + wm * 64 + i * 16 + quad * 4;
        #pragma unroll
        for (int j = 0; j < 4; ++j) {
            const int colg = bn + wn * 64 + j * 16 + l15;
            const float bv = bias[colg];
            #pragma unroll
            for (int r = 0; r < 4; ++r)
                Y[(size_t)(rowg + r) * N + colg] = acc[i][j][r] + bv;
        }
    }
}

// ---------------------------------------------------------------------------
// Streaming attention + R-gating — REVERTED to the R1-measured-best
// structure (118.9us): 4 waves x 32 q-rows (mi=2), K+V staged single-buffer
// via global_load_lds (R8's direct-global V scattered 16 lines/load and
// doubled duration — staging amortizes line traffic 4x across waves),
// 2 barriers/iter, Pt[wave][mi][half] wide layout, MFMA denominator,
// K/V XOR-swizzle. Kept from later rounds: cvt_pk P-packing (R8-verified).
// New: grid roles swapped (blockIdx.x = h, .y = qt) so all 16 q-tile blocks
// of a head land on one XCD (lin%8 = h%8) -> that XCD's L2 holds the head's
// 512KB K/V instead of all 8 L2s re-fetching every head (T1 for attn).
// ---------------------------------------------------------------------------
__launch_bounds__(256, 4)
__global__ void attn_fused(const bf16* __restrict__ QRp, const bf16* __restrict__ Kp,
                           const bf16* __restrict__ Vtp, bf16* __restrict__ Op)
{
    constexpr int S = 2048, DXc = 1024, QRST = 2048, Dh = 64;
    constexpr int PST = 40;                     // P^T row stride (elements)
    __shared__ alignas(16) bf16 KsLo[64 * 32], KsHi[64 * 32];
    __shared__ alignas(16) bf16 VtLo[64 * 32], VtHi[64 * 32];
    __shared__ alignas(16) bf16 Pt[4][2][2][16 * PST];   // [wave][mi][half]

    const int tid  = threadIdx.x;
    const int lane = tid & 63;
    const int wave = tid >> 6;
    const int h = blockIdx.x, qt = blockIdx.y, b = blockIdx.z;   // T1 swap
    const int l15  = lane & 15;
    const int quad = lane >> 4;

    const size_t qrbase = ((size_t)b * S) * QRST + h * Dh;   // Q cols; R at +1024
    const size_t kbase  = ((size_t)b * S) * DXc + h * Dh;
    const size_t vtbase = ((size_t)(b * 16 + h) * Dh) * S;
    const size_t obase  = ((size_t)b * S) * DXc + h * Dh;

    constexpr float QSCALE = 0.125f * 1.44269504088896340736f;
    bf16x8 qf[2][2];
    #pragma unroll
    for (int mi = 0; mi < 2; ++mi) {
        const int qrow = qt * 128 + wave * 32 + mi * 16 + l15;
        const bf16* qptr = QRp + qrbase + (size_t)qrow * QRST + quad * 8;
        qf[mi][0] = *(const bf16x8*)(qptr);
        qf[mi][1] = *(const bf16x8*)(qptr + 32);
        #pragma unroll
        for (int j = 0; j < 8; ++j) {
            qf[mi][0][j] = (bf16)((float)qf[mi][0][j] * QSCALE);
            qf[mi][1][j] = (bf16)((float)qf[mi][1][j] * QSCALE);
        }
    }

    bf16x8 onef;
    #pragma unroll
    for (int j = 0; j < 8; ++j) onef[j] = (bf16)1.0f;

    f32x4 oacc[2][4] = {};     // [mi][db] — O^T: col=qrow(l15), rows d=quad*4+r
    f32x4 lsacc[2] = {};       // denominator via ones x P^T

    const int srow = lane >> 2;
    // pre-swizzled source chunk (see swz8)
    const int scol = ((lane & 3) ^ ((srow >> 1) & 3)) * 8;
    const bf16* kseg = Kp  + kbase  + (size_t)(16 * wave + srow) * DXc + scol;
    const bf16* vseg = Vtp + vtbase + (size_t)(16 * wave + srow) * S   + scol;
    bf16* ksl = KsLo + wave * 512;
    bf16* ksh = KsHi + wave * 512;
    bf16* vtl = VtLo + wave * 512;
    bf16* vth = VtHi + wave * 512;

    for (int kv0 = 0; kv0 < S; kv0 += 64) {
        __syncthreads();
        async_copy16(kseg + (size_t)kv0 * DXc,      ksl);
        async_copy16(kseg + (size_t)kv0 * DXc + 32, ksh);
        async_copy16(vseg + kv0,                    vtl);
        async_copy16(vseg + kv0 + 32,               vth);
        __syncthreads();

        // ---- QK phase: S^T blocks, exp2, cvt_pk pack, write P^T ----
        f32x4 st[2][4];
        #pragma unroll
        for (int nb = 0; nb < 4; ++nb) {
            bf16x8 kf0 = *(const bf16x8*)(KsLo + (nb * 16 + l15) * 32 + swz8(l15, quad));
            bf16x8 kf1 = *(const bf16x8*)(KsHi + (nb * 16 + l15) * 32 + swz8(l15, quad));
            #pragma unroll
            for (int mi = 0; mi < 2; ++mi) {
                f32x4 z = {0.f, 0.f, 0.f, 0.f};
                z = MFMA_16x16x32(kf1, qf[mi][1], z);
                st[mi][nb] = MFMA_16x16x32(kf0, qf[mi][0], z);
            }
        }
        #pragma unroll
        for (int mi = 0; mi < 2; ++mi) {
            #pragma unroll
            for (int nb = 0; nb < 4; ++nb) {
                const float p0 = __builtin_exp2f(st[mi][nb][0]);
                const float p1 = __builtin_exp2f(st[mi][nb][1]);
                const float p2 = __builtin_exp2f(st[mi][nb][2]);
                const float p3 = __builtin_exp2f(st[mi][nb][3]);
                uint2 w;
                w.x = cvt_pk_bf16(p0, p1);
                w.y = cvt_pk_bf16(p2, p3);
                *(uint2*)(&Pt[wave][mi][nb >> 1][0] + l15 * PST
                          + (nb & 1) * 16 + quad * 4) = w;
            }
        }

        // ---- PV phase: K=32, A=Vt b128 frags, B=P^T b128 reads ----
        #pragma unroll
        for (int half = 0; half < 2; ++half) {
            const bf16* vb = half ? VtHi : VtLo;
            bf16x8 vtf[4];
            #pragma unroll
            for (int db = 0; db < 4; ++db)
                vtf[db] = *(const bf16x8*)(vb + (db * 16 + l15) * 32 + swz8(l15, quad));
            #pragma unroll
            for (int mi = 0; mi < 2; ++mi) {
                bf16x8 pf = *(const bf16x8*)(&Pt[wave][mi][half][0]
                                             + l15 * PST + quad * 8);
                #pragma unroll
                for (int db = 0; db < 4; ++db)
                    oacc[mi][db] = MFMA_16x16x32(vtf[db], pf, oacc[mi][db]);
                lsacc[mi] = MFMA_16x16x32(onef, pf, lsacc[mi]);
            }
        }
    }

    // epilogue: O^T — col=qrow=l15 (single inv), rows d contiguous bf16x4.
    #pragma unroll
    for (int mi = 0; mi < 2; ++mi) {
        const float inv = 1.0f / lsacc[mi][0];
        const int qrow = qt * 128 + wave * 32 + mi * 16 + l15;
        const bf16* rrow = QRp + qrbase + (size_t)qrow * QRST + 1024;
        bf16* orow = Op + obase + (size_t)qrow * DXc;
        #pragma unroll
        for (int db = 0; db < 4; ++db) {
            bf16x4 rg = *(const bf16x4*)(rrow + db * 16 + quad * 4);
            bf16x4 o;
            #pragma unroll
            for (int r = 0; r < 4; ++r)
                o[r] = (bf16)(oacc[mi][db][r] * inv * (float)rg[r]);
            *(bf16x4*)(orow + db * 16 + quad * 4) = o;
        }
    }
}

extern "C" void kernel_launch(void* const* d_in, const int* in_sizes, int n_in,
                              void* d_out, int out_size, void* d_ws, size_t ws_size,
                              hipStream_t stream)
{
    (void)in_sizes; (void)n_in; (void)out_size; (void)ws_size;
    constexpr int B = 4, S = 2048, DX = 1024, M = B * S;
    constexpr size_t MD = (size_t)M * DX;
    constexpr size_t WD = (size_t)DX * DX;

    const float* value  = (const float*)d_in[0];
    const float* keyi   = (const float*)d_in[1];
    const float* query  = (const float*)d_in[2];
    const float* Wq_w   = (const float*)d_in[3];
    const float* Wq_b   = (const float*)d_in[4];
    const float* Wk_w   = (const float*)d_in[5];
    const float* Wk_b   = (const float*)d_in[6];
    const float* Wv_w   = (const float*)d_in[7];
    const float* Wv_b   = (const float*)d_in[8];
    const float* Wr_w   = (const float*)d_in[9];
    const float* Wr_b   = (const float*)d_in[10];
    const float* Wout_w = (const float*)d_in[11];
    const float* Wout_b = (const float*)d_in[12];

    bf16* p = (bf16*)d_ws;
    bf16* xv   = p;  p += MD;
    bf16* xk   = p;  p += MD;
    bf16* xq   = p;  p += MD;
    bf16* wall = p;  p += 4 * WD;   // [Wq; Wr; Wk; Wv]
    bf16* wo   = p;  p += WD;
    bf16* qr   = p;  p += 2 * MD;   // fused Q|R, [M][2048]
    bf16* kws  = p;  p += MD;
    bf16* vtws = p;  p += MD;       // V^T: [B][DX][S]
    float* ball = (float*)p;        // packed bias [4096] f32
    bf16* ows = xv;                 // xv dead after projections

    cvt3_acts<<<dim3(2048), dim3(256), 0, stream>>>(value, keyi, query, xv, xk, xq);
    cvt5_wts <<<dim3(1024), dim3(256), 0, stream>>>(Wq_w, Wr_w, Wk_w, Wv_w, Wout_w,
                                                    Wq_b, Wr_b, Wk_b, Wv_b,
                                                    wall, wall + WD, wall + 2 * WD,
                                                    wall + 3 * WD, wo, ball);

    proj_fused<<<dim3(M / 128, 32), dim3(256), 0, stream>>>(
        xq, xk, xv, wall, ball, qr, kws, vtws);

    attn_fused<<<dim3(16, S / 128, B), dim3(256), 0, stream>>>(qr, kws, vtws, ows);

    gemm_out<<<dim3(M / 128, DX / 128), dim3(256), 0, stream>>>(
        ows, wo, Wout_b, (float*)d_out);
}

// Round 10
// 392.080 us; speedup vs baseline: 1.2255x; 1.0246x over previous
//
#include <hip/hip_runtime.h>
#include <hip/hip_bf16.h>

typedef __bf16 bf16;
typedef __bf16 bf16x4 __attribute__((ext_vector_type(4)));
typedef __bf16 bf16x8 __attribute__((ext_vector_type(8)));
typedef float  f32x4  __attribute__((ext_vector_type(4)));

#define MFMA_16x16x32(a, b, c) __builtin_amdgcn_mfma_f32_16x16x32_bf16((a), (b), (c), 0, 0, 0)

typedef const void __attribute__((address_space(1))) gvoid;
typedef void __attribute__((address_space(3))) svoid;

__device__ __forceinline__ void async_copy16(const void* gptr, void* ldsptr) {
    __builtin_amdgcn_global_load_lds((gvoid*)gptr, (svoid*)ldsptr, 16, 0, 0);
}

// XOR swizzle for [16][32] bf16 LDS segments (row stride 64B).
// slot(row,quad) = quad ^ ((row>>1)&3). Both-sides: pre-swizzled global
// source chunk for global_load_lds (linear dest) + same XOR on ds_read.
__device__ __forceinline__ int swz8(int row, int quad) {
    return (quad ^ ((row >> 1) & 3)) * 8;
}

// Packed f32x2 -> bf16x2 (one u32). T12 recipe: no builtin on gfx950.
__device__ __forceinline__ unsigned cvt_pk_bf16(float a, float b) {
    unsigned r;
    asm("v_cvt_pk_bf16_f32 %0, %1, %2" : "=v"(r) : "v"(a), "v"(b));
    return r;
}

// ---------------------------------------------------------------------------
// Fused f32->bf16 converters.
// ---------------------------------------------------------------------------
__global__ void cvt3_acts(const float* __restrict__ s0, const float* __restrict__ s1,
                          const float* __restrict__ s2,
                          bf16* __restrict__ d0, bf16* __restrict__ d1, bf16* __restrict__ d2)
{
    constexpr int N4SEG = 8192 * 1024 / 4;
    int i = blockIdx.x * blockDim.x + threadIdx.x;
    const int stride = gridDim.x * blockDim.x;
    for (; i < 3 * N4SEG; i += stride) {
        const int seg = i / N4SEG;
        const int j = i - seg * N4SEG;
        const float* s = seg == 0 ? s0 : (seg == 1 ? s1 : s2);
        bf16* d = seg == 0 ? d0 : (seg == 1 ? d1 : d2);
        float4 v = ((const float4*)s)[j];
        bf16x4 o = { (bf16)v.x, (bf16)v.y, (bf16)v.z, (bf16)v.w };
        ((bf16x4*)d)[j] = o;
    }
}

// Weights + bias packing fused (removes 4 hipMemcpyAsync graph nodes).
__global__ void cvt5_wts(const float* __restrict__ s0, const float* __restrict__ s1,
                         const float* __restrict__ s2, const float* __restrict__ s3,
                         const float* __restrict__ s4,
                         const float* __restrict__ bq, const float* __restrict__ br,
                         const float* __restrict__ bk, const float* __restrict__ bv,
                         bf16* __restrict__ d0, bf16* __restrict__ d1, bf16* __restrict__ d2,
                         bf16* __restrict__ d3, bf16* __restrict__ d4,
                         float* __restrict__ ball)
{
    constexpr int N4SEG = 1024 * 1024 / 4;
    int i = blockIdx.x * blockDim.x + threadIdx.x;
    const int stride = gridDim.x * blockDim.x;
    if (i < 4096) {
        const int seg = i >> 10, j = i & 1023;
        const float* b = seg == 0 ? bq : seg == 1 ? br : seg == 2 ? bk : bv;
        ball[i] = b[j];
    }
    for (; i < 5 * N4SEG; i += stride) {
        const int seg = i / N4SEG;
        const int j = i - seg * N4SEG;
        const float* s = seg == 0 ? s0 : seg == 1 ? s1 : seg == 2 ? s2 : seg == 3 ? s3 : s4;
        bf16* d = seg == 0 ? d0 : seg == 1 ? d1 : seg == 2 ? d2 : seg == 3 ? d3 : d4;
        float4 v = ((const float4*)s)[j];
        bf16x4 o = { (bf16)v.x, (bf16)v.y, (bf16)v.z, (bf16)v.w };
        ((bf16x4*)d)[j] = o;
    }
}

// ---------------------------------------------------------------------------
// Fused projection GEMM, one dispatch for QR | K | V^T. K-tiles dbuf'd.
// (R9 lesson: XCD swizzle REVERTED — working set L3-fits, swizzle cost ~5us,
// matching m160's "-2% when L3-fit".)
// ---------------------------------------------------------------------------
__global__ void proj_fused(const bf16* __restrict__ xq, const bf16* __restrict__ xk,
                           const bf16* __restrict__ xv, const bf16* __restrict__ wall,
                           const float* __restrict__ ball,
                           bf16* __restrict__ qr, bf16* __restrict__ kws,
                           bf16* __restrict__ vtws)
{
    constexpr int K = 1024, SDIM = 2048;
    __shared__ alignas(16) bf16 As[2][128 * 32];
    __shared__ alignas(16) bf16 Bs[2][128 * 32];

    const int tid  = threadIdx.x;
    const int lane = tid & 63;
    const int wave = tid >> 6;
    const int wm   = wave >> 1;
    const int wn   = wave & 1;
    const int bm   = blockIdx.x * 128;
    const int by   = blockIdx.y;
    const int bn   = by * 128;              // global n
    const int l15  = lane & 15;
    const int quad = lane >> 4;

    const bf16* X = (by < 16) ? xq : (by < 24 ? xk : xv);

    const int srow = lane >> 2;
    const int scol = (lane & 3) * 8;

    const bf16* aseg0 = X + (size_t)(bm + wave * 32 + srow) * K + scol;
    const bf16* aseg1 = X + (size_t)(bm + wave * 32 + 16 + srow) * K + scol;
    const bf16* bseg0 = wall + (size_t)(bn + wave * 32 + srow) * K + scol;
    const bf16* bseg1 = wall + (size_t)(bn + wave * 32 + 16 + srow) * K + scol;

    f32x4 acc[4][4] = {};

    // prologue: stage tile 0 into buffer 0
    async_copy16(aseg0, As[0] + (wave * 2 + 0) * 512);
    async_copy16(aseg1, As[0] + (wave * 2 + 1) * 512);
    async_copy16(bseg0, Bs[0] + (wave * 2 + 0) * 512);
    async_copy16(bseg1, Bs[0] + (wave * 2 + 1) * 512);

    for (int k0 = 0; k0 < K; k0 += 32) {
        const int cur = (k0 >> 5) & 1;
        __syncthreads();                     // tile-cur loads retired everywhere
        if (k0 + 32 < K) {
            const int nxt = cur ^ 1;
            async_copy16(aseg0 + k0 + 32, As[nxt] + (wave * 2 + 0) * 512);
            async_copy16(aseg1 + k0 + 32, As[nxt] + (wave * 2 + 1) * 512);
            async_copy16(bseg0 + k0 + 32, Bs[nxt] + (wave * 2 + 0) * 512);
            async_copy16(bseg1 + k0 + 32, Bs[nxt] + (wave * 2 + 1) * 512);
        }

        bf16x8 af[4], bfr[4];
        #pragma unroll
        for (int i = 0; i < 4; ++i)
            af[i] = *(const bf16x8*)(As[cur] + (wm * 64 + i * 16 + l15) * 32 + quad * 8);
        #pragma unroll
        for (int j = 0; j < 4; ++j)
            bfr[j] = *(const bf16x8*)(Bs[cur] + (wn * 64 + j * 16 + l15) * 32 + quad * 8);
        #pragma unroll
        for (int i = 0; i < 4; ++i)
            #pragma unroll
            for (int j = 0; j < 4; ++j)
                acc[i][j] = MFMA_16x16x32(af[i], bfr[j], acc[i][j]);
    }

    #pragma unroll
    for (int i = 0; i < 4; ++i) {
        const int rowg = bm + wm * 64 + i * 16 + quad * 4;
        #pragma unroll
        for (int j = 0; j < 4; ++j) {
            const int colg = bn + wn * 64 + j * 16 + l15;
            const float bv = ball[colg];
            if (by < 16) {
                #pragma unroll
                for (int r = 0; r < 4; ++r)
                    qr[(size_t)(rowg + r) * 2048 + colg] = (bf16)(acc[i][j][r] + bv);
            } else if (by < 24) {
                const int cl = colg - 2048;
                #pragma unroll
                for (int r = 0; r < 4; ++r)
                    kws[(size_t)(rowg + r) * 1024 + cl] = (bf16)(acc[i][j][r] + bv);
            } else {
                const int d = colg - 3072;
                bf16x4 o;
                #pragma unroll
                for (int r = 0; r < 4; ++r) o[r] = (bf16)(acc[i][j][r] + bv);
                *(bf16x4*)(vtws + (size_t)(rowg >> 11) * 1024 * SDIM
                                + (size_t)d * SDIM + (rowg & (SDIM - 1))) = o;
            }
        }
    }
}

// ---------------------------------------------------------------------------
// Output GEMM: Y[m][n] = sum_k X[m][k]*W[n][k] + b[n], f32 out. Dbuf'd.
// (XCD swizzle reverted, same reason as proj_fused.)
// ---------------------------------------------------------------------------
__global__ void gemm_out(const bf16* __restrict__ X, const bf16* __restrict__ W,
                         const float* __restrict__ bias, float* __restrict__ Y)
{
    constexpr int K = 1024, N = 1024;
    __shared__ alignas(16) bf16 As[2][128 * 32];
    __shared__ alignas(16) bf16 Bs[2][128 * 32];

    const int tid  = threadIdx.x;
    const int lane = tid & 63;
    const int wave = tid >> 6;
    const int wm   = wave >> 1;
    const int wn   = wave & 1;
    const int bm   = blockIdx.x * 128;
    const int bn   = blockIdx.y * 128;
    const int l15  = lane & 15;
    const int quad = lane >> 4;

    const int srow = lane >> 2;
    const int scol = (lane & 3) * 8;

    const bf16* aseg0 = X + (size_t)(bm + wave * 32 + srow) * K + scol;
    const bf16* aseg1 = X + (size_t)(bm + wave * 32 + 16 + srow) * K + scol;
    const bf16* bseg0 = W + (size_t)(bn + wave * 32 + srow) * K + scol;
    const bf16* bseg1 = W + (size_t)(bn + wave * 32 + 16 + srow) * K + scol;

    f32x4 acc[4][4] = {};

    async_copy16(aseg0, As[0] + (wave * 2 + 0) * 512);
    async_copy16(aseg1, As[0] + (wave * 2 + 1) * 512);
    async_copy16(bseg0, Bs[0] + (wave * 2 + 0) * 512);
    async_copy16(bseg1, Bs[0] + (wave * 2 + 1) * 512);

    for (int k0 = 0; k0 < K; k0 += 32) {
        const int cur = (k0 >> 5) & 1;
        __syncthreads();
        if (k0 + 32 < K) {
            const int nxt = cur ^ 1;
            async_copy16(aseg0 + k0 + 32, As[nxt] + (wave * 2 + 0) * 512);
            async_copy16(aseg1 + k0 + 32, As[nxt] + (wave * 2 + 1) * 512);
            async_copy16(bseg0 + k0 + 32, Bs[nxt] + (wave * 2 + 0) * 512);
            async_copy16(bseg1 + k0 + 32, Bs[nxt] + (wave * 2 + 1) * 512);
        }

        bf16x8 af[4], bfr[4];
        #pragma unroll
        for (int i = 0; i < 4; ++i)
            af[i] = *(const bf16x8*)(As[cur] + (wm * 64 + i * 16 + l15) * 32 + quad * 8);
        #pragma unroll
        for (int j = 0; j < 4; ++j)
            bfr[j] = *(const bf16x8*)(Bs[cur] + (wn * 64 + j * 16 + l15) * 32 + quad * 8);
        #pragma unroll
        for (int i = 0; i < 4; ++i)
            #pragma unroll
            for (int j = 0; j < 4; ++j)
                acc[i][j] = MFMA_16x16x32(af[i], bfr[j], acc[i][j]);
    }

    #pragma unroll
    for (int i = 0; i < 4; ++i) {
        const int rowg = bm + wm * 64 + i * 16 + quad * 4;
        #pragma unroll
        for (int j = 0; j < 4; ++j) {
            const int colg = bn + wn * 64 + j * 16 + l15;
            const float bv = bias[colg];
            #pragma unroll
            for (int r = 0; r < 4; ++r)
                Y[(size_t)(rowg + r) * N + colg] = acc[i][j][r] + bv;
        }
    }
}

// ---------------------------------------------------------------------------
// Streaming attention + R-gating. R9-best structure (117.0us): 4 waves x 32
// q-rows (mi=2), K+V staged single-buffer, 2 barriers/iter, wide Pt, MFMA
// denominator, K/V XOR-swizzle, cvt_pk packing, head-grouped grid
// (blockIdx.x=h -> per-XCD L2 holds one head's K/V: FETCH 147->33MB, R9).
// NEW this round (T5, m191 precedent): s_setprio(1) around the QK and PV
// MFMA clusters. The 4 independent blocks/CU sit at different loop phases;
// priority lets MFMA-phase waves preempt exp2/staging-phase waves on the
// shared SIMD issue port. exp2/pack section stays prio 0.
// ---------------------------------------------------------------------------
__launch_bounds__(256, 4)
__global__ void attn_fused(const bf16* __restrict__ QRp, const bf16* __restrict__ Kp,
                           const bf16* __restrict__ Vtp, bf16* __restrict__ Op)
{
    constexpr int S = 2048, DXc = 1024, QRST = 2048, Dh = 64;
    constexpr int PST = 40;                     // P^T row stride (elements)
    __shared__ alignas(16) bf16 KsLo[64 * 32], KsHi[64 * 32];
    __shared__ alignas(16) bf16 VtLo[64 * 32], VtHi[64 * 32];
    __shared__ alignas(16) bf16 Pt[4][2][2][16 * PST];   // [wave][mi][half]

    const int tid  = threadIdx.x;
    const int lane = tid & 63;
    const int wave = tid >> 6;
    const int h = blockIdx.x, qt = blockIdx.y, b = blockIdx.z;   // head-grouped
    const int l15  = lane & 15;
    const int quad = lane >> 4;

    const size_t qrbase = ((size_t)b * S) * QRST + h * Dh;   // Q cols; R at +1024
    const size_t kbase  = ((size_t)b * S) * DXc + h * Dh;
    const size_t vtbase = ((size_t)(b * 16 + h) * Dh) * S;
    const size_t obase  = ((size_t)b * S) * DXc + h * Dh;

    constexpr float QSCALE = 0.125f * 1.44269504088896340736f;
    bf16x8 qf[2][2];
    #pragma unroll
    for (int mi = 0; mi < 2; ++mi) {
        const int qrow = qt * 128 + wave * 32 + mi * 16 + l15;
        const bf16* qptr = QRp + qrbase + (size_t)qrow * QRST + quad * 8;
        qf[mi][0] = *(const bf16x8*)(qptr);
        qf[mi][1] = *(const bf16x8*)(qptr + 32);
        #pragma unroll
        for (int j = 0; j < 8; ++j) {
            qf[mi][0][j] = (bf16)((float)qf[mi][0][j] * QSCALE);
            qf[mi][1][j] = (bf16)((float)qf[mi][1][j] * QSCALE);
        }
    }

    bf16x8 onef;
    #pragma unroll
    for (int j = 0; j < 8; ++j) onef[j] = (bf16)1.0f;

    f32x4 oacc[2][4] = {};     // [mi][db] — O^T: col=qrow(l15), rows d=quad*4+r
    f32x4 lsacc[2] = {};       // denominator via ones x P^T

    const int srow = lane >> 2;
    // pre-swizzled source chunk (see swz8)
    const int scol = ((lane & 3) ^ ((srow >> 1) & 3)) * 8;
    const bf16* kseg = Kp  + kbase  + (size_t)(16 * wave + srow) * DXc + scol;
    const bf16* vseg = Vtp + vtbase + (size_t)(16 * wave + srow) * S   + scol;
    bf16* ksl = KsLo + wave * 512;
    bf16* ksh = KsHi + wave * 512;
    bf16* vtl = VtLo + wave * 512;
    bf16* vth = VtHi + wave * 512;

    for (int kv0 = 0; kv0 < S; kv0 += 64) {
        __syncthreads();
        async_copy16(kseg + (size_t)kv0 * DXc,      ksl);
        async_copy16(kseg + (size_t)kv0 * DXc + 32, ksh);
        async_copy16(vseg + kv0,                    vtl);
        async_copy16(vseg + kv0 + 32,               vth);
        __syncthreads();

        // ---- QK phase (prio 1): S^T blocks ----
        f32x4 st[2][4];
        __builtin_amdgcn_s_setprio(1);
        #pragma unroll
        for (int nb = 0; nb < 4; ++nb) {
            bf16x8 kf0 = *(const bf16x8*)(KsLo + (nb * 16 + l15) * 32 + swz8(l15, quad));
            bf16x8 kf1 = *(const bf16x8*)(KsHi + (nb * 16 + l15) * 32 + swz8(l15, quad));
            #pragma unroll
            for (int mi = 0; mi < 2; ++mi) {
                f32x4 z = {0.f, 0.f, 0.f, 0.f};
                z = MFMA_16x16x32(kf1, qf[mi][1], z);
                st[mi][nb] = MFMA_16x16x32(kf0, qf[mi][0], z);
            }
        }
        __builtin_amdgcn_s_setprio(0);

        // ---- exp2 / cvt_pk pack / write P^T (prio 0) ----
        #pragma unroll
        for (int mi = 0; mi < 2; ++mi) {
            #pragma unroll
            for (int nb = 0; nb < 4; ++nb) {
                const float p0 = __builtin_exp2f(st[mi][nb][0]);
                const float p1 = __builtin_exp2f(st[mi][nb][1]);
                const float p2 = __builtin_exp2f(st[mi][nb][2]);
                const float p3 = __builtin_exp2f(st[mi][nb][3]);
                uint2 w;
                w.x = cvt_pk_bf16(p0, p1);
                w.y = cvt_pk_bf16(p2, p3);
                *(uint2*)(&Pt[wave][mi][nb >> 1][0] + l15 * PST
                          + (nb & 1) * 16 + quad * 4) = w;
            }
        }

        // ---- PV phase (prio 1): K=32, A=Vt b128 frags, B=P^T b128 reads ----
        __builtin_amdgcn_s_setprio(1);
        #pragma unroll
        for (int half = 0; half < 2; ++half) {
            const bf16* vb = half ? VtHi : VtLo;
            bf16x8 vtf[4];
            #pragma unroll
            for (int db = 0; db < 4; ++db)
                vtf[db] = *(const bf16x8*)(vb + (db * 16 + l15) * 32 + swz8(l15, quad));
            #pragma unroll
            for (int mi = 0; mi < 2; ++mi) {
                bf16x8 pf = *(const bf16x8*)(&Pt[wave][mi][half][0]
                                             + l15 * PST + quad * 8);
                #pragma unroll
                for (int db = 0; db < 4; ++db)
                    oacc[mi][db] = MFMA_16x16x32(vtf[db], pf, oacc[mi][db]);
                lsacc[mi] = MFMA_16x16x32(onef, pf, lsacc[mi]);
            }
        }
        __builtin_amdgcn_s_setprio(0);
    }

    // epilogue: O^T — col=qrow=l15 (single inv), rows d contiguous bf16x4.
    #pragma unroll
    for (int mi = 0; mi < 2; ++mi) {
        const float inv = 1.0f / lsacc[mi][0];
        const int qrow = qt * 128 + wave * 32 + mi * 16 + l15;
        const bf16* rrow = QRp + qrbase + (size_t)qrow * QRST + 1024;
        bf16* orow = Op + obase + (size_t)qrow * DXc;
        #pragma unroll
        for (int db = 0; db < 4; ++db) {
            bf16x4 rg = *(const bf16x4*)(rrow + db * 16 + quad * 4);
            bf16x4 o;
            #pragma unroll
            for (int r = 0; r < 4; ++r)
                o[r] = (bf16)(oacc[mi][db][r] * inv * (float)rg[r]);
            *(bf16x4*)(orow + db * 16 + quad * 4) = o;
        }
    }
}

extern "C" void kernel_launch(void* const* d_in, const int* in_sizes, int n_in,
                              void* d_out, int out_size, void* d_ws, size_t ws_size,
                              hipStream_t stream)
{
    (void)in_sizes; (void)n_in; (void)out_size; (void)ws_size;
    constexpr int B = 4, S = 2048, DX = 1024, M = B * S;
    constexpr size_t MD = (size_t)M * DX;
    constexpr size_t WD = (size_t)DX * DX;

    const float* value  = (const float*)d_in[0];
    const float* keyi   = (const float*)d_in[1];
    const float* query  = (const float*)d_in[2];
    const float* Wq_w   = (const float*)d_in[3];
    const float* Wq_b   = (const float*)d_in[4];
    const float* Wk_w   = (const float*)d_in[5];
    const float* Wk_b   = (const float*)d_in[6];
    const float* Wv_w   = (const float*)d_in[7];
    const float* Wv_b   = (const float*)d_in[8];
    const float* Wr_w   = (const float*)d_in[9];
    const float* Wr_b   = (const float*)d_in[10];
    const float* Wout_w = (const float*)d_in[11];
    const float* Wout_b = (const float*)d_in[12];

    bf16* p = (bf16*)d_ws;
    bf16* xv   = p;  p += MD;
    bf16* xk   = p;  p += MD;
    bf16* xq   = p;  p += MD;
    bf16* wall = p;  p += 4 * WD;   // [Wq; Wr; Wk; Wv]
    bf16* wo   = p;  p += WD;
    bf16* qr   = p;  p += 2 * MD;   // fused Q|R, [M][2048]
    bf16* kws  = p;  p += MD;
    bf16* vtws = p;  p += MD;       // V^T: [B][DX][S]
    float* ball = (float*)p;        // packed bias [4096] f32
    bf16* ows = xv;                 // xv dead after projections

    cvt3_acts<<<dim3(2048), dim3(256), 0, stream>>>(value, keyi, query, xv, xk, xq);
    cvt5_wts <<<dim3(1024), dim3(256), 0, stream>>>(Wq_w, Wr_w, Wk_w, Wv_w, Wout_w,
                                                    Wq_b, Wr_b, Wk_b, Wv_b,
                                                    wall, wall + WD, wall + 2 * WD,
                                                    wall + 3 * WD, wo, ball);

    proj_fused<<<dim3(M / 128, 32), dim3(256), 0, stream>>>(
        xq, xk, xv, wall, ball, qr, kws, vtws);

    attn_fused<<<dim3(16, S / 128, B), dim3(256), 0, stream>>>(qr, kws, vtws, ows);

    gemm_out<<<dim3(M / 128, DX / 128), dim3(256), 0, stream>>>(
        ows, wo, Wout_b, (float*)d_out);
}